// Round 7
// baseline (404.153 us; speedup 1.0000x reference)
//
#include <hip/hip_runtime.h>
#include <math.h>

#define D_MODEL 2048
#define NE 8
#define TOKENS 16384
#define RBLK 512           // router blocks (32 tokens each)

// output layout (floats): probs[16384*8], idx[16384*2], topp[16384*2], aux[1]
#define OUT_IDX   131072
#define OUT_TOPP  163840
#define OUT_AUX   196608

// ws layout (bytes)
#define WS_SPR    0        // double[1]  (zeroed by memset)
#define WS_CNT    8        // uint[1]    (zeroed by memset)
#define WS_BP     64       // float[512*8]  router per-block P-sums (plain stores)
#define WS_BC     16448    // float[512*8]  router per-block expert counts
#define WS_GP     33024    // float[8]   published via atomicExch by spr_finish blk 0
#define WS_GC     33056    // float[8]
#define WS_SIMP   65536    // float[KS][65536], fully written by gemm blocks

// ---------------------------------------------------------------------------
// Fused kernel: blocks [0,RBLK) = router; blocks [RBLK, RBLK+16*ks) = SPR gemm.
// Router: 512 thr (8 waves), W in 64KB LDS, 4 tokens/wave, it-loop in two
//   half-passes with 16 hoisted x-loads (max MLP). f32 logits.
// Gemm: 64x64 pair tile, 512 thr, 2x4 thread tiles, per-bk partial buffers.
// ---------------------------------------------------------------------------
__global__ __launch_bounds__(512, 4) void fused_k(
    const float* __restrict__ x, const float* __restrict__ W,
    const int* __restrict__ spr_idx, float* __restrict__ out,
    float* __restrict__ blockP, float* __restrict__ blockC,
    float* __restrict__ simP, int nkc)
{
    __shared__ float smem[NE * D_MODEL + 2 * NE];   // 64 KB + P/C scratch
    const int tid = threadIdx.x;

    if (blockIdx.x < RBLK) {
        // ========================= router =========================
        float4* Wl = (float4*)smem;                 // [NE*512]
        float* Pl = smem + NE * D_MODEL;            // [8]
        float* Cl = Pl + NE;                        // [8]
        {
            const float4* W4 = (const float4*)W;
#pragma unroll
            for (int i = 0; i < 8; ++i) Wl[tid + i * 512] = W4[tid + i * 512];
        }
        if (tid < NE) { Pl[tid] = 0.f; Cl[tid] = 0.f; }
        __syncthreads();

        const int wave = tid >> 6, lane = tid & 63;
        const int keep5 = (lane >> 5) & 1, keep4 = (lane >> 4) & 1, keep3 = (lane >> 3) & 1;
        const int emine = keep3 + 2 * keep4 + 4 * keep5;
        const int t0 = blockIdx.x * 32 + wave * 4;
        const float4* xp = (const float4*)(x + (size_t)t0 * D_MODEL);

        float acc[4][NE] = {};
#pragma unroll
        for (int half = 0; half < 2; ++half) {
            float4 xv[4][4];                        // [it][token] — 16 loads in flight
#pragma unroll
            for (int it = 0; it < 4; ++it)
#pragma unroll
                for (int t = 0; t < 4; ++t)
                    xv[it][t] = xp[t * 512 + (half * 4 + it) * 64 + lane];
#pragma unroll
            for (int it = 0; it < 4; ++it)
#pragma unroll
                for (int e = 0; e < NE; ++e) {
                    const float4 wv = Wl[e * 512 + (half * 4 + it) * 64 + lane];
#pragma unroll
                    for (int t = 0; t < 4; ++t)
                        acc[t][e] += xv[it][t].x * wv.x + xv[it][t].y * wv.y +
                                     xv[it][t].z * wv.z + xv[it][t].w * wv.w;
                }
        }

        float localP = 0.f, localC = 0.f;
#pragma unroll
        for (int tt = 0; tt < 4; ++tt) {
            const int t = t0 + tt;
            float a[NE];
#pragma unroll
            for (int e = 0; e < NE; ++e) a[e] = acc[tt][e];

            // log-fold reduce: experts fold into 8-lane groups
#pragma unroll
            for (int j = 0; j < 4; ++j) {
                float keep = keep5 ? a[j + 4] : a[j];
                float send = keep5 ? a[j] : a[j + 4];
                a[j] = keep + __shfl_xor(send, 32, 64);
            }
#pragma unroll
            for (int j = 0; j < 2; ++j) {
                float keep = keep4 ? a[j + 2] : a[j];
                float send = keep4 ? a[j] : a[j + 2];
                a[j] = keep + __shfl_xor(send, 16, 64);
            }
            {
                float keep = keep3 ? a[1] : a[0];
                float send = keep3 ? a[0] : a[1];
                a[0] = keep + __shfl_xor(send, 8, 64);
            }
            float L = a[0];
            L += __shfl_xor(L, 4, 64);
            L += __shfl_xor(L, 2, 64);
            L += __shfl_xor(L, 1, 64);

            // top-1 / top-2 (lowest index wins ties = jax.lax.top_k)
            float v1 = L; int i1 = emine;
#pragma unroll
            for (int off = 8; off <= 32; off <<= 1) {
                float ov = __shfl_xor(v1, off, 64);
                int oi = __shfl_xor(i1, off, 64);
                if (ov > v1 || (ov == v1 && oi < i1)) { v1 = ov; i1 = oi; }
            }
            float v2 = (emine == i1) ? -3.4e38f : L;
            int i2 = (emine == i1) ? NE : emine;
#pragma unroll
            for (int off = 8; off <= 32; off <<= 1) {
                float ov = __shfl_xor(v2, off, 64);
                int oi = __shfl_xor(i2, off, 64);
                if (ov > v2 || (ov == v2 && oi < i2)) { v2 = ov; i2 = oi; }
            }
            float p = __expf(L - v1);
            float s = p;
#pragma unroll
            for (int off = 8; off <= 32; off <<= 1) s += __shfl_xor(s, off, 64);
            const float pr = p / s;

            localP += pr;
            localC += ((emine == i1) ? 1.f : 0.f) + ((emine == i2) ? 1.f : 0.f);

            if ((lane & 7) == 0) out[(size_t)t * NE + emine] = pr;
            if (lane == 0) {
                out[OUT_IDX + t * 2]     = (float)i1;
                out[OUT_IDX + t * 2 + 1] = (float)i2;
                const float e2 = __expf(v2 - v1);
                out[OUT_TOPP + t * 2]     = 1.0f / (1.0f + e2);
                out[OUT_TOPP + t * 2 + 1] = e2 / (1.0f + e2);
            }
        }
        if ((lane & 7) == 0) {
            atomicAdd(&Pl[emine], localP);
            atomicAdd(&Cl[emine], localC);
        }
        __syncthreads();
        if (tid < NE) {
            blockP[blockIdx.x * NE + tid] = Pl[tid];
            blockC[blockIdx.x * NE + tid] = Cl[tid];
        }
    } else {
        // ========================= SPR gemm =========================
        float (*A)[65] = (float (*)[65])smem;
        float (*B)[65] = (float (*)[65])(smem + 64 * 65);
        __shared__ int ra[64], rb[64];
        const int b2 = blockIdx.x - RBLK;
        const int bi = b2 & 3, bj = (b2 >> 2) & 3, bk = b2 >> 4;
        if (tid < 64) ra[tid] = spr_idx[bi * 64 + tid];
        else if (tid < 128) rb[tid - 64] = spr_idx[bj * 64 + (tid - 64)];
        __syncthreads();

        const int tx = tid & 15, ty = tid >> 4;     // 16 x 32
        float acc[2][4] = {};

        for (int kc = 0; kc < nkc; ++kc) {
            const int k0 = (bk * nkc + kc) * 64;
#pragma unroll
            for (int l = 0; l < 2; ++l) {
                const int lin = l * 512 + tid;
                const int r = lin >> 4, c4 = lin & 15;
                float4 v = *(const float4*)(x + (size_t)ra[r] * D_MODEL + k0 + c4 * 4);
                A[r][c4 * 4] = v.x; A[r][c4 * 4 + 1] = v.y; A[r][c4 * 4 + 2] = v.z; A[r][c4 * 4 + 3] = v.w;
                float4 w = *(const float4*)(x + (size_t)rb[r] * D_MODEL + k0 + c4 * 4);
                B[r][c4 * 4] = w.x; B[r][c4 * 4 + 1] = w.y; B[r][c4 * 4 + 2] = w.z; B[r][c4 * 4 + 3] = w.w;
            }
            __syncthreads();
#pragma unroll 4
            for (int k = 0; k < 64; ++k) {
                const float a0 = A[ty * 2][k], a1 = A[ty * 2 + 1][k];
                float b[4];
#pragma unroll
                for (int u = 0; u < 4; ++u) b[u] = B[tx * 4 + u][k];
#pragma unroll
                for (int u = 0; u < 4; ++u) { acc[0][u] += a0 * b[u]; acc[1][u] += a1 * b[u]; }
            }
            __syncthreads();
        }
        float* dst = simP + (size_t)bk * 65536;
#pragma unroll
        for (int u = 0; u < 2; ++u)
#pragma unroll
            for (int v = 0; v < 4; ++v)
                dst[(bi * 64 + ty * 2 + u) * 256 + (bj * 64 + tx * 4 + v)] = acc[u][v];
    }
}

// ---------------------------------------------------------------------------
// SPR loss + finalize. 256 blocks (row i) x 256 threads (col j).
// Block 0 reduces router per-block P/C -> gP/gC via atomicExch (device-
// coherent publish). Last block (counter) computes the aux loss.
// ---------------------------------------------------------------------------
__global__ __launch_bounds__(256) void spr_finish(
    const float* __restrict__ simP, const int* __restrict__ spr_idx,
    const float* __restrict__ out_probs, const float* __restrict__ blockP,
    const float* __restrict__ blockC, float* __restrict__ gP, float* __restrict__ gC,
    double* __restrict__ spr_sum, unsigned* __restrict__ counter,
    float* __restrict__ out, int ks)
{
    const int i = blockIdx.x, j = threadIdx.x;
    __shared__ float rni[NE];
    __shared__ double red[4];

    if (i == 0) {   // reduce router partials (512 blocks x 8 experts)
        __shared__ float rP[32][NE], rC[32][NE];
        const int e = j & 7, c = j >> 3;
        float sp = 0.f, sc = 0.f;
#pragma unroll
        for (int b = 0; b < 16; ++b) {
            sp += blockP[(c * 16 + b) * NE + e];
            sc += blockC[(c * 16 + b) * NE + e];
        }
        rP[c][e] = sp; rC[c][e] = sc;
        __syncthreads();
        if (j < NE) {
            float P = 0.f, C = 0.f;
            for (int cc = 0; cc < 32; ++cc) { P += rP[cc][j]; C += rC[cc][j]; }
            atomicExch(&gP[j], P);     // device-coherent publish (G16)
            atomicExch(&gC[j], C);
        }
        __syncthreads();
    }

    float raw = 0.f, dj = 0.f;
    for (int s = 0; s < ks; ++s) raw += simP[(size_t)s * 65536 + i * 256 + j];
    for (int s = 0; s < ks; ++s) dj  += simP[(size_t)s * 65536 + j * 257];

    const int rowj = spr_idx[j];
    const float4* pp = (const float4*)(out_probs + (size_t)rowj * NE);
    float4 pv0 = pp[0], pv1 = pp[1];
    float rs = pv0.x * pv0.x + pv0.y * pv0.y + pv0.z * pv0.z + pv0.w * pv0.w +
               pv1.x * pv1.x + pv1.y * pv1.y + pv1.z * pv1.z + pv1.w * pv1.w;
    const float rinv = 1.0f / fmaxf(sqrtf(rs), 1e-12f);
    float rnj[NE] = { pv0.x * rinv, pv0.y * rinv, pv0.z * rinv, pv0.w * rinv,
                      pv1.x * rinv, pv1.y * rinv, pv1.z * rinv, pv1.w * rinv };
    if (j == i) {
#pragma unroll
        for (int e = 0; e < NE; ++e) rni[e] = rnj[e];
        red[3] = (double)dj;
    }
    __syncthreads();
    const float di = (float)red[3];
    float rsim = 0.f;
#pragma unroll
    for (int e = 0; e < NE; ++e) rsim += rni[e] * rnj[e];
    const float ni = fmaxf(sqrtf(di), 1e-12f), nj = fmaxf(sqrtf(dj), 1e-12f);
    const float isim = raw / (ni * nj);
    const double d = (double)rsim - (double)isim;
    double sq = d * d;
#pragma unroll
    for (int off = 32; off; off >>= 1) sq += __shfl_xor(sq, off, 64);
    __syncthreads();
    const int wave = j >> 6, lane = j & 63;
    if (lane == 0) red[wave] = sq;
    __syncthreads();
    if (j == 0) {
        atomicAdd(spr_sum, red[0] + red[1] + red[2] + red[3]);
        __threadfence();
        const unsigned old = atomicAdd(counter, 1u);
        if (old == 255u) {
            const double spr = atomicAdd(spr_sum, 0.0) / 65536.0;
            double lb = 0.0, dpsl = 0.0;
            for (int e = 0; e < NE; ++e) {
                const double Pi = (double)atomicAdd(&gP[e], 0.f) / (double)TOKENS;
                const double fi = (double)atomicAdd(&gC[e], 0.f) / (double)(TOKENS * 2);
                lb += fi * Pi;
                dpsl += 0.125 * (log(0.125) - log(Pi));
            }
            lb *= 8.0;
            out[OUT_AUX] = (float)(0.01 * (lb + dpsl + 0.1 * spr));
        }
    }
}

extern "C" void kernel_launch(void* const* d_in, const int* in_sizes, int n_in,
                              void* d_out, int out_size, void* d_ws, size_t ws_size,
                              hipStream_t stream)
{
    const float* x = (const float*)d_in[0];
    const float* W = (const float*)d_in[1];
    const int* spr_idx = (const int*)d_in[2];
    float* out = (float*)d_out;
    char* ws = (char*)d_ws;

    double*   spr_sum = (double*)(ws + WS_SPR);
    unsigned* counter = (unsigned*)(ws + WS_CNT);
    float*    blockP  = (float*)(ws + WS_BP);
    float*    blockC  = (float*)(ws + WS_BC);
    float*    gP      = (float*)(ws + WS_GP);
    float*    gC      = (float*)(ws + WS_GC);
    float*    simP    = (float*)(ws + WS_SIMP);

    int ks = 8;
    if (ws_size >= (size_t)WS_SIMP + 32u * 65536u * 4u) ks = 32;
    else if (ws_size >= (size_t)WS_SIMP + 16u * 65536u * 4u) ks = 16;
    const int nkc = 32 / ks;

    hipMemsetAsync(ws, 0, 16, stream);   // spr_sum + counter

    fused_k<<<RBLK + 16 * ks, 512, 0, stream>>>(x, W, spr_idx, out,
                                                blockP, blockC, simP, nkc);
    spr_finish<<<256, 256, 0, stream>>>(simP, spr_idx, out, blockP, blockC,
                                        gP, gC, spr_sum, counter, out, ks);
}